// Round 8
// baseline (306.577 us; speedup 1.0000x reference)
//
#include <hip/hip_runtime.h>
#include <stdint.h>

typedef __bf16 bf16;
typedef __bf16 bf16x8 __attribute__((ext_vector_type(8)));
typedef float floatx16 __attribute__((ext_vector_type(16)));
typedef unsigned short u16;

#define PDIM 16

__device__ __forceinline__ floatx16 mfma_32x32x16(bf16x8 a, bf16x8 b, floatx16 c) {
  return __builtin_amdgcn_mfma_f32_32x32x16_bf16(a, b, c, 0, 0, 0);
}

// async 16B/lane global->LDS; LDS dst = wave-uniform base + lane*16.
__device__ __forceinline__ void stage16(const bf16* g, bf16* lds_base) {
  __builtin_amdgcn_global_load_lds(
      (const __attribute__((address_space(1))) void*)g,
      (__attribute__((address_space(3))) void*)lds_base, 16, 0, 0);
}

// ---- fused prep: [0,2048) transpose W0/W1; [2048,2048+nConvBlk) emb conv;
// then biases+W2 pack. All fp32 -> bf16. ----
__global__ __launch_bounds__(256) void kprep(const float* __restrict__ emb,
                                             const float* __restrict__ W0,
                                             const float* __restrict__ W1,
                                             const float* __restrict__ b0,
                                             const float* __restrict__ b1,
                                             const float* __restrict__ W2,
                                             const float* __restrict__ b2,
                                             bf16* __restrict__ embB,
                                             bf16* __restrict__ W0T,
                                             bf16* __restrict__ W1T,
                                             bf16* __restrict__ smallB,
                                             int n8, int nConvBlk) {
  __shared__ u16 tile[64][72];
  const int b = blockIdx.x;
  const int t = threadIdx.x;
  if (b < 2048) {
    const int m  = b >> 10;
    const int p  = (b >> 6) & 15;
    const int tr = (b >> 3) & 7;
    const int tc = b & 7;
    const float* src = (m ? W1 : W0) + ((size_t)p << 18);
    bf16*        dst = (m ? W1T : W0T) + ((size_t)p << 18);
#pragma unroll
    for (int i = 0; i < 2; ++i) {
      int c = t + i * 256;
      int r = c >> 3, s = c & 7;
      const float4* s32 =
          (const float4*)(src + (size_t)(tr * 64 + r) * 512 + tc * 64 + s * 8);
      float4 a = s32[0], bb = s32[1];
      bf16 o[8] = {(bf16)a.x, (bf16)a.y, (bf16)a.z, (bf16)a.w,
                   (bf16)bb.x, (bf16)bb.y, (bf16)bb.z, (bf16)bb.w};
      *(uint4*)&tile[r][s * 8] = *(uint4*)o;
    }
    __syncthreads();
#pragma unroll
    for (int i = 0; i < 2; ++i) {
      int c = t + i * 256;
      int r = c >> 3, s = c & 7;
      union { u16 u[8]; uint4 v; } tmp;
#pragma unroll
      for (int j = 0; j < 8; ++j) tmp.u[j] = tile[s * 8 + j][r];
      *(uint4*)(dst + (size_t)(tc * 64 + r) * 512 + tr * 64 + s * 8) = tmp.v;
    }
  } else if (b < 2048 + nConvBlk) {
    const int i = (b - 2048) * 256 + t;
    if (i < n8) {
      const float4* s = (const float4*)emb;
      float4 a = s[i * 2], bb = s[i * 2 + 1];
      bf16 o[8] = {(bf16)a.x, (bf16)a.y, (bf16)a.z, (bf16)a.w,
                   (bf16)bb.x, (bf16)bb.y, (bf16)bb.z, (bf16)bb.w};
      *(uint4*)(embB + (size_t)i * 8) = *(uint4*)o;
    }
  } else {
    const int j = (b - 2048 - nConvBlk) * 256 + t;
    if (j < 24592) {
      const float* src;
      int off;
      if (j < 8192)       { src = b0; off = j; }
      else if (j < 16384) { src = b1; off = j - 8192; }
      else if (j < 24576) { src = W2; off = j - 16384; }
      else                { src = b2; off = j - 24576; }
      smallB[j] = (bf16)src[off];
    }
  }
}

// ---- layer 0: h0 = relu(emb . W0T^T + b0), bf16 out.
// 128x128 tile, BK=32, cross-iteration double-buffered async staging
// (one barrier/iter, drain overlaps a full compute phase), 32x32x16 MFMA.
__global__ __launch_bounds__(256) void kgemm1(const bf16* __restrict__ emb,
                                              const bf16* __restrict__ W0T,
                                              const bf16* __restrict__ small,
                                              bf16* __restrict__ h0,
                                              int Nc) {
  __shared__ bf16 smem[16384];  // Ab[2][4096] | Bb[2][4096]; epilogue C 64x136
  const int b  = blockIdx.x;
  const int p  = b & 15;
  const int ht = (b >> 4) & 3;
  const int nt = b >> 6;
  const int n0 = nt * 128;
  const int hc0 = ht * 128;
  const int tid = threadIdx.x;
  const int w = tid >> 6;
  const int lane = tid & 63;
  const int m2 = lane & 31;
  const int q2 = lane >> 5;
  const int wr = (w >> 1) * 64;
  const int wc = (w & 1) * 64;
  const int srow = lane >> 2;       // 0..15
  const int kch  = (lane & 3) * 8;  // 16B chunk within 32-elem row

  const bf16* Arow = emb + (size_t)n0 * 512;
  const bf16* Brow = W0T + ((size_t)p << 18) + (size_t)hc0 * 512;

  floatx16 acc[2][2];
#pragma unroll
  for (int i = 0; i < 2; ++i)
#pragma unroll
    for (int j = 0; j < 2; ++j)
#pragma unroll
      for (int e = 0; e < 16; ++e) acc[i][j][e] = 0.f;

  const int r0 = w * 16 + srow;
  // prologue: stage tile 0 into buffer 0
  stage16(Arow + (size_t)r0 * 512 + kch, smem + (w * 16) * 32);
  stage16(Arow + (size_t)(64 + r0) * 512 + kch, smem + (64 + w * 16) * 32);
  stage16(Brow + (size_t)r0 * 512 + kch, smem + 8192 + (w * 16) * 32);
  stage16(Brow + (size_t)(64 + r0) * 512 + kch, smem + 8192 + (64 + w * 16) * 32);

  for (int it = 0; it < 16; ++it) {
    __syncthreads();  // tile[it] landed; everyone done reading buf[it^1]
    const int bb = it & 1;
    if (it + 1 < 16) {
      const int nb = (it + 1) & 1;
      const int kn = (it + 1) * 32;
      stage16(Arow + (size_t)r0 * 512 + kn + kch,
              smem + nb * 4096 + (w * 16) * 32);
      stage16(Arow + (size_t)(64 + r0) * 512 + kn + kch,
              smem + nb * 4096 + (64 + w * 16) * 32);
      stage16(Brow + (size_t)r0 * 512 + kn + kch,
              smem + 8192 + nb * 4096 + (w * 16) * 32);
      stage16(Brow + (size_t)(64 + r0) * 512 + kn + kch,
              smem + 8192 + nb * 4096 + (64 + w * 16) * 32);
    }
    const bf16* A = smem + bb * 4096;
    const bf16* B = smem + 8192 + bb * 4096;
#pragma unroll
    for (int kk = 0; kk < 2; ++kk) {
      bf16x8 af0 = *(const bf16x8*)&A[(wr + m2) * 32 + kk * 16 + q2 * 8];
      bf16x8 af1 = *(const bf16x8*)&A[(wr + 32 + m2) * 32 + kk * 16 + q2 * 8];
      bf16x8 bv0 = *(const bf16x8*)&B[(wc + m2) * 32 + kk * 16 + q2 * 8];
      bf16x8 bv1 = *(const bf16x8*)&B[(wc + 32 + m2) * 32 + kk * 16 + q2 * 8];
      acc[0][0] = mfma_32x32x16(af0, bv0, acc[0][0]);
      acc[0][1] = mfma_32x32x16(af0, bv1, acc[0][1]);
      acc[1][0] = mfma_32x32x16(af1, bv0, acc[1][0]);
      acc[1][1] = mfma_32x32x16(af1, bv1, acc[1][1]);
    }
  }

  // coalesced epilogue via LDS (stride 136), two 64-row passes
  __syncthreads();
  bf16* Cst = smem;
#pragma unroll
  for (int pass = 0; pass < 2; ++pass) {
    if ((w >> 1) == pass) {
#pragma unroll
      for (int ct = 0; ct < 2; ++ct) {
        const float bvv = (float)small[p * 512 + hc0 + wc + ct * 32 + m2];
#pragma unroll
        for (int rt = 0; rt < 2; ++rt)
#pragma unroll
          for (int reg = 0; reg < 16; ++reg) {
            const int rowf = (reg & 3) + 8 * (reg >> 2) + 4 * q2;
            float v = acc[rt][ct][reg] + bvv;
            v = v > 0.f ? v : 0.f;
            Cst[(rt * 32 + rowf) * 136 + wc + ct * 32 + m2] = (bf16)v;
          }
      }
    }
    __syncthreads();
#pragma unroll
    for (int i = 0; i < 4; ++i) {
      const int row = (tid >> 4) + i * 16;
      const int chunk = tid & 15;
      uint4 v = *(const uint4*)&Cst[row * 136 + chunk * 8];
      *(uint4*)&h0[((size_t)p * Nc + n0 + pass * 64 + row) * 512 + hc0 +
                   chunk * 8] = v;
    }
    if (pass == 0) __syncthreads();
  }
}

// ---- layer 1 GEMM + fused partial layer-2 dot; same pipelined core ----
__global__ __launch_bounds__(256) void kgemm2(const bf16* __restrict__ h0,
                                              const bf16* __restrict__ W1T,
                                              const bf16* __restrict__ small,
                                              float* __restrict__ pacc,
                                              int Nc) {
  __shared__ bf16 smem[16384];
  __shared__ float oacc[128];
  const int b  = blockIdx.x;
  const int p  = b & 15;
  const int ht = (b >> 4) & 3;
  const int nt = b >> 6;
  const int n0 = nt * 128;
  const int hc0 = ht * 128;
  const int tid = threadIdx.x;
  const int w = tid >> 6;
  const int lane = tid & 63;
  const int m2 = lane & 31;
  const int q2 = lane >> 5;
  const int wr = (w >> 1) * 64;
  const int wc = (w & 1) * 64;
  const int srow = lane >> 2;
  const int kch = (lane & 3) * 8;
  if (tid < 128) oacc[tid] = 0.f;

  const bf16* Arow = h0 + ((size_t)p * Nc + n0) * 512;
  const bf16* Brow = W1T + ((size_t)p << 18) + (size_t)hc0 * 512;

  floatx16 acc[2][2];
#pragma unroll
  for (int i = 0; i < 2; ++i)
#pragma unroll
    for (int j = 0; j < 2; ++j)
#pragma unroll
      for (int e = 0; e < 16; ++e) acc[i][j][e] = 0.f;

  const int r0 = w * 16 + srow;
  stage16(Arow + (size_t)r0 * 512 + kch, smem + (w * 16) * 32);
  stage16(Arow + (size_t)(64 + r0) * 512 + kch, smem + (64 + w * 16) * 32);
  stage16(Brow + (size_t)r0 * 512 + kch, smem + 8192 + (w * 16) * 32);
  stage16(Brow + (size_t)(64 + r0) * 512 + kch, smem + 8192 + (64 + w * 16) * 32);

  for (int it = 0; it < 16; ++it) {
    __syncthreads();
    const int bb = it & 1;
    if (it + 1 < 16) {
      const int nb = (it + 1) & 1;
      const int kn = (it + 1) * 32;
      stage16(Arow + (size_t)r0 * 512 + kn + kch,
              smem + nb * 4096 + (w * 16) * 32);
      stage16(Arow + (size_t)(64 + r0) * 512 + kn + kch,
              smem + nb * 4096 + (64 + w * 16) * 32);
      stage16(Brow + (size_t)r0 * 512 + kn + kch,
              smem + 8192 + nb * 4096 + (w * 16) * 32);
      stage16(Brow + (size_t)(64 + r0) * 512 + kn + kch,
              smem + 8192 + nb * 4096 + (64 + w * 16) * 32);
    }
    const bf16* A = smem + bb * 4096;
    const bf16* B = smem + 8192 + bb * 4096;
#pragma unroll
    for (int kk = 0; kk < 2; ++kk) {
      bf16x8 af0 = *(const bf16x8*)&A[(wr + m2) * 32 + kk * 16 + q2 * 8];
      bf16x8 af1 = *(const bf16x8*)&A[(wr + 32 + m2) * 32 + kk * 16 + q2 * 8];
      bf16x8 bv0 = *(const bf16x8*)&B[(wc + m2) * 32 + kk * 16 + q2 * 8];
      bf16x8 bv1 = *(const bf16x8*)&B[(wc + 32 + m2) * 32 + kk * 16 + q2 * 8];
      acc[0][0] = mfma_32x32x16(af0, bv0, acc[0][0]);
      acc[0][1] = mfma_32x32x16(af0, bv1, acc[0][1]);
      acc[1][0] = mfma_32x32x16(af1, bv0, acc[1][0]);
      acc[1][1] = mfma_32x32x16(af1, bv1, acc[1][1]);
    }
  }

  // epilogue: h1 = relu(acc + b1); pd[row] += h1 * W2[col]
  float pd[2][16];
#pragma unroll
  for (int rt = 0; rt < 2; ++rt)
#pragma unroll
    for (int reg = 0; reg < 16; ++reg) pd[rt][reg] = 0.f;
#pragma unroll
  for (int ct = 0; ct < 2; ++ct) {
    const int col = hc0 + wc + ct * 32 + m2;
    const float b1v = (float)small[8192 + p * 512 + col];
    const float w2v = (float)small[16384 + p * 512 + col];
#pragma unroll
    for (int rt = 0; rt < 2; ++rt)
#pragma unroll
      for (int reg = 0; reg < 16; ++reg) {
        float v = acc[rt][ct][reg] + b1v;
        v = v > 0.f ? v : 0.f;
        pd[rt][reg] += v * w2v;
      }
  }
  // reduce over the 32 col-lanes (xor masks stay within 32-lane halves)
#pragma unroll
  for (int rt = 0; rt < 2; ++rt)
#pragma unroll
    for (int reg = 0; reg < 16; ++reg) {
      float v = pd[rt][reg];
      v += __shfl_xor(v, 1);
      v += __shfl_xor(v, 2);
      v += __shfl_xor(v, 4);
      v += __shfl_xor(v, 8);
      v += __shfl_xor(v, 16);
      if (m2 == 0)
        atomicAdd(&oacc[wr + rt * 32 + (reg & 3) + 8 * (reg >> 2) + 4 * q2], v);
    }
  __syncthreads();
  if (tid < 128)
    pacc[(size_t)(p * 4 + ht) * Nc + n0 + tid] = oacc[tid];
}

// ---- finish: sum 4 ht partials + b2, sigmoid, fp32 out ----
__global__ __launch_bounds__(256) void kfin(const float* __restrict__ pacc,
                                            const bf16* __restrict__ small,
                                            float* __restrict__ out, int Nc) {
  const int idx = blockIdx.x * 256 + threadIdx.x;
  if (idx >= Nc * 16) return;
  const int n = idx >> 4;
  const int p = idx & 15;
  float v = (float)small[24576 + p];
#pragma unroll
  for (int ht = 0; ht < 4; ++ht) v += pacc[(size_t)(p * 4 + ht) * Nc + n];
  out[(size_t)n * 16 + p] = 1.f / (1.f + expf(-v));
}

// ---- fallback (tiny ws / odd N): slow but correct, fp32 in/out ----
__global__ __launch_bounds__(64) void knaive(const float* __restrict__ emb,
                                             const float* __restrict__ W0,
                                             const float* __restrict__ b0,
                                             const float* __restrict__ W1,
                                             const float* __restrict__ b1,
                                             const float* __restrict__ W2,
                                             const float* __restrict__ b2,
                                             float* __restrict__ out) {
  const int n = blockIdx.x >> 4;
  const int p = blockIdx.x & 15;
  __shared__ float h0s[512];
  __shared__ float h1s[512];
  const size_t wb = (size_t)p << 18;
  const int t = threadIdx.x;
  for (int h = t; h < 512; h += 64) {
    float a = 0.f;
    for (int e = 0; e < 512; ++e)
      a += emb[(size_t)n * 512 + e] * W0[wb + (size_t)e * 512 + h];
    a += b0[p * 512 + h];
    h0s[h] = a > 0.f ? a : 0.f;
  }
  __syncthreads();
  for (int k = t; k < 512; k += 64) {
    float a = 0.f;
    for (int hh = 0; hh < 512; ++hh)
      a += h0s[hh] * W1[wb + (size_t)hh * 512 + k];
    a += b1[p * 512 + k];
    h1s[k] = a > 0.f ? a : 0.f;
  }
  __syncthreads();
  float s = 0.f;
  for (int k = t; k < 512; k += 64) s += h1s[k] * W2[p * 512 + k];
  for (int off = 32; off; off >>= 1) s += __shfl_down(s, off, 64);
  if (t == 0)
    out[(size_t)n * 16 + p] = 1.f / (1.f + expf(-(s + b2[p])));
}

extern "C" void kernel_launch(void* const* d_in, const int* in_sizes, int n_in,
                              void* d_out, int out_size, void* d_ws, size_t ws_size,
                              hipStream_t stream) {
  (void)n_in; (void)out_size;
  const float* emb = (const float*)d_in[0];
  const float* W0  = (const float*)d_in[1];
  const float* b0  = (const float*)d_in[2];
  const float* W1  = (const float*)d_in[3];
  const float* b1  = (const float*)d_in[4];
  const float* W2  = (const float*)d_in[5];
  const float* b2  = (const float*)d_in[6];
  float* out = (float*)d_out;

  const int N = in_sizes[0] / 512;

  char* ws = (char*)d_ws;
  bf16*  W0T    = (bf16*)ws;                                 // 8 MB
  bf16*  W1T    = (bf16*)(ws + (8ll << 20));                 // 8 MB
  bf16*  smallB = (bf16*)(ws + (16ll << 20));                // 64 KB
  float* pacc   = (float*)(ws + (16ll << 20) + 65536);       // 256*N B
  bf16*  embB   = (bf16*)(ws + (16ll << 20) + 65536 + (size_t)N * 256);
  bf16*  h0     = (bf16*)(ws + (16ll << 20) + 65536 + (size_t)N * 256 +
                          (size_t)N * 1024);
  const long long fixed = (16ll << 20) + 65536 + (long long)N * 256 +
                          (long long)N * 1024;
  long long avail = (long long)ws_size - fixed;
  long long rows = avail > 0 ? avail / (16 * 512 * 2) : 0;
  int Nc = (int)((rows / 128) * 128);
  if (Nc > N) Nc = N;

  if (Nc < 128 || (N % 128) != 0) {
    knaive<<<dim3(N * PDIM), dim3(64), 0, stream>>>(emb, W0, b0, W1, b1, W2,
                                                    b2, out);
    return;
  }

  const int n8 = N * 512 / 8;
  const int nConvBlk = (n8 + 255) / 256;
  kprep<<<dim3(2048 + nConvBlk + 97), dim3(256), 0, stream>>>(
      emb, W0, W1, b0, b1, W2, b2, embB, W0T, W1T, smallB, n8, nConvBlk);

  for (int noff = 0; noff < N; noff += Nc) {
    const int cur = (N - noff < Nc) ? (N - noff) : Nc;
    kgemm1<<<dim3(64 * (cur / 128)), dim3(256), 0, stream>>>(
        embB + (size_t)noff * 512, W0T, smallB, h0, cur);
    kgemm2<<<dim3(64 * (cur / 128)), dim3(256), 0, stream>>>(
        h0, W1T, smallB, pacc, cur);
    kfin<<<dim3((cur * 16 + 255) / 256), dim3(256), 0, stream>>>(
        pacc, smallB, out + (size_t)noff * 16, cur);
  }
}

// Round 9
// 295.612 us; speedup vs baseline: 1.0371x; 1.0371x over previous
//
#include <hip/hip_runtime.h>
#include <stdint.h>

typedef __bf16 bf16;
typedef __bf16 bf16x8 __attribute__((ext_vector_type(8)));
typedef float floatx16 __attribute__((ext_vector_type(16)));
typedef unsigned short u16;

#define PDIM 16

__device__ __forceinline__ floatx16 mfma_32x32x16(bf16x8 a, bf16x8 b, floatx16 c) {
  return __builtin_amdgcn_mfma_f32_32x32x16_bf16(a, b, c, 0, 0, 0);
}

// async 16B/lane global->LDS; LDS dst = wave-uniform base + lane*16.
__device__ __forceinline__ void stage16(const bf16* g, bf16* lds_base) {
  __builtin_amdgcn_global_load_lds(
      (const __attribute__((address_space(1))) void*)g,
      (__attribute__((address_space(3))) void*)lds_base, 16, 0, 0);
}

// ---- fused prep: [0,2048) transpose W0/W1; [2048,2048+nConvBlk) emb conv;
// then biases+W2 pack. All fp32 -> bf16. ----
__global__ __launch_bounds__(256) void kprep(const float* __restrict__ emb,
                                             const float* __restrict__ W0,
                                             const float* __restrict__ W1,
                                             const float* __restrict__ b0,
                                             const float* __restrict__ b1,
                                             const float* __restrict__ W2,
                                             const float* __restrict__ b2,
                                             bf16* __restrict__ embB,
                                             bf16* __restrict__ W0T,
                                             bf16* __restrict__ W1T,
                                             bf16* __restrict__ smallB,
                                             int n8, int nConvBlk) {
  __shared__ u16 tile[64][72];
  const int b = blockIdx.x;
  const int t = threadIdx.x;
  if (b < 2048) {
    const int m  = b >> 10;
    const int p  = (b >> 6) & 15;
    const int tr = (b >> 3) & 7;
    const int tc = b & 7;
    const float* src = (m ? W1 : W0) + ((size_t)p << 18);
    bf16*        dst = (m ? W1T : W0T) + ((size_t)p << 18);
#pragma unroll
    for (int i = 0; i < 2; ++i) {
      int c = t + i * 256;
      int r = c >> 3, s = c & 7;
      const float4* s32 =
          (const float4*)(src + (size_t)(tr * 64 + r) * 512 + tc * 64 + s * 8);
      float4 a = s32[0], bb = s32[1];
      bf16 o[8] = {(bf16)a.x, (bf16)a.y, (bf16)a.z, (bf16)a.w,
                   (bf16)bb.x, (bf16)bb.y, (bf16)bb.z, (bf16)bb.w};
      *(uint4*)&tile[r][s * 8] = *(uint4*)o;
    }
    __syncthreads();
#pragma unroll
    for (int i = 0; i < 2; ++i) {
      int c = t + i * 256;
      int r = c >> 3, s = c & 7;
      union { u16 u[8]; uint4 v; } tmp;
#pragma unroll
      for (int j = 0; j < 8; ++j) tmp.u[j] = tile[s * 8 + j][r];
      *(uint4*)(dst + (size_t)(tc * 64 + r) * 512 + tr * 64 + s * 8) = tmp.v;
    }
  } else if (b < 2048 + nConvBlk) {
    const int i = (b - 2048) * 256 + t;
    if (i < n8) {
      const float4* s = (const float4*)emb;
      float4 a = s[i * 2], bb = s[i * 2 + 1];
      bf16 o[8] = {(bf16)a.x, (bf16)a.y, (bf16)a.z, (bf16)a.w,
                   (bf16)bb.x, (bf16)bb.y, (bf16)bb.z, (bf16)bb.w};
      *(uint4*)(embB + (size_t)i * 8) = *(uint4*)o;
    }
  } else {
    const int j = (b - 2048 - nConvBlk) * 256 + t;
    if (j < 24592) {
      const float* src;
      int off;
      if (j < 8192)       { src = b0; off = j; }
      else if (j < 16384) { src = b1; off = j - 8192; }
      else if (j < 24576) { src = W2; off = j - 16384; }
      else                { src = b2; off = j - 24576; }
      smallB[j] = (bf16)src[off];
    }
  }
}

// XOR-swizzled LDS layout: data (row r, 16B-chunk c) lives at LDS slot
// (r, c ^ (r&3)). Staging fetches chunk ((lane&3) ^ (srow&3)); fragment
// reads use chunk ((kk*2+q2) ^ (m2&3)). Spreads the 32-row fragment read
// across all 32 banks (4 lanes/bank = b128 floor) instead of 8.

// ---- layer 0: h0 = relu(emb . W0T^T + b0), bf16 out.
// 128x128 tile, BK=32, cross-iteration double-buffered async staging,
// 32x32x16 MFMA, swizzled LDS.
__global__ __launch_bounds__(256) void kgemm1(const bf16* __restrict__ emb,
                                              const bf16* __restrict__ W0T,
                                              const bf16* __restrict__ small,
                                              bf16* __restrict__ h0,
                                              int Nc) {
  __shared__ bf16 smem[16384];  // Ab[2][4096] | Bb[2][4096]; epilogue C 64x136
  const int b  = blockIdx.x;
  const int p  = b & 15;
  const int ht = (b >> 4) & 3;
  const int nt = b >> 6;
  const int n0 = nt * 128;
  const int hc0 = ht * 128;
  const int tid = threadIdx.x;
  const int w = tid >> 6;
  const int lane = tid & 63;
  const int m2 = lane & 31;
  const int q2 = lane >> 5;
  const int wr = (w >> 1) * 64;
  const int wc = (w & 1) * 64;
  const int srow = lane >> 2;                                // 0..15
  const int kchS = (((lane & 3) ^ (srow & 3)) * 8);          // swizzled chunk
  const int sw = (m2 & 3) * 2;                               // read swizzle *16B

  const bf16* Arow = emb + (size_t)n0 * 512;
  const bf16* Brow = W0T + ((size_t)p << 18) + (size_t)hc0 * 512;

  floatx16 acc[2][2];
#pragma unroll
  for (int i = 0; i < 2; ++i)
#pragma unroll
    for (int j = 0; j < 2; ++j)
#pragma unroll
      for (int e = 0; e < 16; ++e) acc[i][j][e] = 0.f;

  const int r0 = w * 16 + srow;
  stage16(Arow + (size_t)r0 * 512 + kchS, smem + (w * 16) * 32);
  stage16(Arow + (size_t)(64 + r0) * 512 + kchS, smem + (64 + w * 16) * 32);
  stage16(Brow + (size_t)r0 * 512 + kchS, smem + 8192 + (w * 16) * 32);
  stage16(Brow + (size_t)(64 + r0) * 512 + kchS, smem + 8192 + (64 + w * 16) * 32);

  for (int it = 0; it < 16; ++it) {
    __syncthreads();  // tile[it] landed; buf[it^1] fully consumed
    const int bb = it & 1;
    if (it + 1 < 16) {
      const int nb = (it + 1) & 1;
      const int kn = (it + 1) * 32;
      stage16(Arow + (size_t)r0 * 512 + kn + kchS,
              smem + nb * 4096 + (w * 16) * 32);
      stage16(Arow + (size_t)(64 + r0) * 512 + kn + kchS,
              smem + nb * 4096 + (64 + w * 16) * 32);
      stage16(Brow + (size_t)r0 * 512 + kn + kchS,
              smem + 8192 + nb * 4096 + (w * 16) * 32);
      stage16(Brow + (size_t)(64 + r0) * 512 + kn + kchS,
              smem + 8192 + nb * 4096 + (64 + w * 16) * 32);
    }
    const bf16* A = smem + bb * 4096;
    const bf16* B = smem + 8192 + bb * 4096;
#pragma unroll
    for (int kk = 0; kk < 2; ++kk) {
      const int ci = (((kk * 2 + q2) ^ (m2 & 3)) * 8);
      bf16x8 af0 = *(const bf16x8*)&A[(wr + m2) * 32 + ci];
      bf16x8 af1 = *(const bf16x8*)&A[(wr + 32 + m2) * 32 + ci];
      bf16x8 bv0 = *(const bf16x8*)&B[(wc + m2) * 32 + ci];
      bf16x8 bv1 = *(const bf16x8*)&B[(wc + 32 + m2) * 32 + ci];
      acc[0][0] = mfma_32x32x16(af0, bv0, acc[0][0]);
      acc[0][1] = mfma_32x32x16(af0, bv1, acc[0][1]);
      acc[1][0] = mfma_32x32x16(af1, bv0, acc[1][0]);
      acc[1][1] = mfma_32x32x16(af1, bv1, acc[1][1]);
    }
  }
  (void)sw;

  // coalesced epilogue via LDS (stride 136), two 64-row passes
  __syncthreads();
  bf16* Cst = smem;
#pragma unroll
  for (int pass = 0; pass < 2; ++pass) {
    if ((w >> 1) == pass) {
#pragma unroll
      for (int ct = 0; ct < 2; ++ct) {
        const float bvv = (float)small[p * 512 + hc0 + wc + ct * 32 + m2];
#pragma unroll
        for (int rt = 0; rt < 2; ++rt)
#pragma unroll
          for (int reg = 0; reg < 16; ++reg) {
            const int rowf = (reg & 3) + 8 * (reg >> 2) + 4 * q2;
            float v = acc[rt][ct][reg] + bvv;
            v = v > 0.f ? v : 0.f;
            Cst[(rt * 32 + rowf) * 136 + wc + ct * 32 + m2] = (bf16)v;
          }
      }
    }
    __syncthreads();
#pragma unroll
    for (int i = 0; i < 4; ++i) {
      const int row = (tid >> 4) + i * 16;
      const int chunk = tid & 15;
      uint4 v = *(const uint4*)&Cst[row * 136 + chunk * 8];
      *(uint4*)&h0[((size_t)p * Nc + n0 + pass * 64 + row) * 512 + hc0 +
                   chunk * 8] = v;
    }
    if (pass == 0) __syncthreads();
  }
}

// ---- layer 1 GEMM + fused partial layer-2 dot; same pipelined core ----
__global__ __launch_bounds__(256) void kgemm2(const bf16* __restrict__ h0,
                                              const bf16* __restrict__ W1T,
                                              const bf16* __restrict__ small,
                                              float* __restrict__ pacc,
                                              int Nc) {
  __shared__ bf16 smem[16384];
  __shared__ float oacc[128];
  const int b  = blockIdx.x;
  const int p  = b & 15;
  const int ht = (b >> 4) & 3;
  const int nt = b >> 6;
  const int n0 = nt * 128;
  const int hc0 = ht * 128;
  const int tid = threadIdx.x;
  const int w = tid >> 6;
  const int lane = tid & 63;
  const int m2 = lane & 31;
  const int q2 = lane >> 5;
  const int wr = (w >> 1) * 64;
  const int wc = (w & 1) * 64;
  const int srow = lane >> 2;
  const int kchS = (((lane & 3) ^ (srow & 3)) * 8);
  if (tid < 128) oacc[tid] = 0.f;

  const bf16* Arow = h0 + ((size_t)p * Nc + n0) * 512;
  const bf16* Brow = W1T + ((size_t)p << 18) + (size_t)hc0 * 512;

  floatx16 acc[2][2];
#pragma unroll
  for (int i = 0; i < 2; ++i)
#pragma unroll
    for (int j = 0; j < 2; ++j)
#pragma unroll
      for (int e = 0; e < 16; ++e) acc[i][j][e] = 0.f;

  const int r0 = w * 16 + srow;
  stage16(Arow + (size_t)r0 * 512 + kchS, smem + (w * 16) * 32);
  stage16(Arow + (size_t)(64 + r0) * 512 + kchS, smem + (64 + w * 16) * 32);
  stage16(Brow + (size_t)r0 * 512 + kchS, smem + 8192 + (w * 16) * 32);
  stage16(Brow + (size_t)(64 + r0) * 512 + kchS, smem + 8192 + (64 + w * 16) * 32);

  for (int it = 0; it < 16; ++it) {
    __syncthreads();
    const int bb = it & 1;
    if (it + 1 < 16) {
      const int nb = (it + 1) & 1;
      const int kn = (it + 1) * 32;
      stage16(Arow + (size_t)r0 * 512 + kn + kchS,
              smem + nb * 4096 + (w * 16) * 32);
      stage16(Arow + (size_t)(64 + r0) * 512 + kn + kchS,
              smem + nb * 4096 + (64 + w * 16) * 32);
      stage16(Brow + (size_t)r0 * 512 + kn + kchS,
              smem + 8192 + nb * 4096 + (w * 16) * 32);
      stage16(Brow + (size_t)(64 + r0) * 512 + kn + kchS,
              smem + 8192 + nb * 4096 + (64 + w * 16) * 32);
    }
    const bf16* A = smem + bb * 4096;
    const bf16* B = smem + 8192 + bb * 4096;
#pragma unroll
    for (int kk = 0; kk < 2; ++kk) {
      const int ci = (((kk * 2 + q2) ^ (m2 & 3)) * 8);
      bf16x8 af0 = *(const bf16x8*)&A[(wr + m2) * 32 + ci];
      bf16x8 af1 = *(const bf16x8*)&A[(wr + 32 + m2) * 32 + ci];
      bf16x8 bv0 = *(const bf16x8*)&B[(wc + m2) * 32 + ci];
      bf16x8 bv1 = *(const bf16x8*)&B[(wc + 32 + m2) * 32 + ci];
      acc[0][0] = mfma_32x32x16(af0, bv0, acc[0][0]);
      acc[0][1] = mfma_32x32x16(af0, bv1, acc[0][1]);
      acc[1][0] = mfma_32x32x16(af1, bv0, acc[1][0]);
      acc[1][1] = mfma_32x32x16(af1, bv1, acc[1][1]);
    }
  }

  // epilogue: h1 = relu(acc + b1); pd[row] += h1 * W2[col]
  float pd[2][16];
#pragma unroll
  for (int rt = 0; rt < 2; ++rt)
#pragma unroll
    for (int reg = 0; reg < 16; ++reg) pd[rt][reg] = 0.f;
#pragma unroll
  for (int ct = 0; ct < 2; ++ct) {
    const int col = hc0 + wc + ct * 32 + m2;
    const float b1v = (float)small[8192 + p * 512 + col];
    const float w2v = (float)small[16384 + p * 512 + col];
#pragma unroll
    for (int rt = 0; rt < 2; ++rt)
#pragma unroll
      for (int reg = 0; reg < 16; ++reg) {
        float v = acc[rt][ct][reg] + b1v;
        v = v > 0.f ? v : 0.f;
        pd[rt][reg] += v * w2v;
      }
  }
#pragma unroll
  for (int rt = 0; rt < 2; ++rt)
#pragma unroll
    for (int reg = 0; reg < 16; ++reg) {
      float v = pd[rt][reg];
      v += __shfl_xor(v, 1);
      v += __shfl_xor(v, 2);
      v += __shfl_xor(v, 4);
      v += __shfl_xor(v, 8);
      v += __shfl_xor(v, 16);
      if (m2 == 0)
        atomicAdd(&oacc[wr + rt * 32 + (reg & 3) + 8 * (reg >> 2) + 4 * q2], v);
    }
  __syncthreads();
  if (tid < 128)
    pacc[(size_t)(p * 4 + ht) * Nc + n0 + tid] = oacc[tid];
}

// ---- finish: sum 4 ht partials + b2, sigmoid, fp32 out ----
__global__ __launch_bounds__(256) void kfin(const float* __restrict__ pacc,
                                            const bf16* __restrict__ small,
                                            float* __restrict__ out, int Nc) {
  const int idx = blockIdx.x * 256 + threadIdx.x;
  if (idx >= Nc * 16) return;
  const int n = idx >> 4;
  const int p = idx & 15;
  float v = (float)small[24576 + p];
#pragma unroll
  for (int ht = 0; ht < 4; ++ht) v += pacc[(size_t)(p * 4 + ht) * Nc + n];
  out[(size_t)n * 16 + p] = 1.f / (1.f + expf(-v));
}

// ---- fallback (tiny ws / odd N): slow but correct, fp32 in/out ----
__global__ __launch_bounds__(64) void knaive(const float* __restrict__ emb,
                                             const float* __restrict__ W0,
                                             const float* __restrict__ b0,
                                             const float* __restrict__ W1,
                                             const float* __restrict__ b1,
                                             const float* __restrict__ W2,
                                             const float* __restrict__ b2,
                                             float* __restrict__ out) {
  const int n = blockIdx.x >> 4;
  const int p = blockIdx.x & 15;
  __shared__ float h0s[512];
  __shared__ float h1s[512];
  const size_t wb = (size_t)p << 18;
  const int t = threadIdx.x;
  for (int h = t; h < 512; h += 64) {
    float a = 0.f;
    for (int e = 0; e < 512; ++e)
      a += emb[(size_t)n * 512 + e] * W0[wb + (size_t)e * 512 + h];
    a += b0[p * 512 + h];
    h0s[h] = a > 0.f ? a : 0.f;
  }
  __syncthreads();
  for (int k = t; k < 512; k += 64) {
    float a = 0.f;
    for (int hh = 0; hh < 512; ++hh)
      a += h0s[hh] * W1[wb + (size_t)hh * 512 + k];
    a += b1[p * 512 + k];
    h1s[k] = a > 0.f ? a : 0.f;
  }
  __syncthreads();
  float s = 0.f;
  for (int k = t; k < 512; k += 64) s += h1s[k] * W2[p * 512 + k];
  for (int off = 32; off; off >>= 1) s += __shfl_down(s, off, 64);
  if (t == 0)
    out[(size_t)n * 16 + p] = 1.f / (1.f + expf(-(s + b2[p])));
}

extern "C" void kernel_launch(void* const* d_in, const int* in_sizes, int n_in,
                              void* d_out, int out_size, void* d_ws, size_t ws_size,
                              hipStream_t stream) {
  (void)n_in; (void)out_size;
  const float* emb = (const float*)d_in[0];
  const float* W0  = (const float*)d_in[1];
  const float* b0  = (const float*)d_in[2];
  const float* W1  = (const float*)d_in[3];
  const float* b1  = (const float*)d_in[4];
  const float* W2  = (const float*)d_in[5];
  const float* b2  = (const float*)d_in[6];
  float* out = (float*)d_out;

  const int N = in_sizes[0] / 512;

  char* ws = (char*)d_ws;
  bf16*  W0T    = (bf16*)ws;                                 // 8 MB
  bf16*  W1T    = (bf16*)(ws + (8ll << 20));                 // 8 MB
  bf16*  smallB = (bf16*)(ws + (16ll << 20));                // 64 KB
  float* pacc   = (float*)(ws + (16ll << 20) + 65536);       // 256*N B
  bf16*  embB   = (bf16*)(ws + (16ll << 20) + 65536 + (size_t)N * 256);
  bf16*  h0     = (bf16*)(ws + (16ll << 20) + 65536 + (size_t)N * 256 +
                          (size_t)N * 1024);
  const long long fixed = (16ll << 20) + 65536 + (long long)N * 256 +
                          (long long)N * 1024;
  long long avail = (long long)ws_size - fixed;
  long long rows = avail > 0 ? avail / (16 * 512 * 2) : 0;
  int Nc = (int)((rows / 128) * 128);
  if (Nc > N) Nc = N;

  if (Nc < 128 || (N % 128) != 0) {
    knaive<<<dim3(N * PDIM), dim3(64), 0, stream>>>(emb, W0, b0, W1, b1, W2,
                                                    b2, out);
    return;
  }

  const int n8 = N * 512 / 8;
  const int nConvBlk = (n8 + 255) / 256;
  kprep<<<dim3(2048 + nConvBlk + 97), dim3(256), 0, stream>>>(
      emb, W0, W1, b0, b1, W2, b2, embB, W0T, W1T, smallB, n8, nConvBlk);

  for (int noff = 0; noff < N; noff += Nc) {
    const int cur = (N - noff < Nc) ? (N - noff) : Nc;
    kgemm1<<<dim3(64 * (cur / 128)), dim3(256), 0, stream>>>(
        embB + (size_t)noff * 512, W0T, smallB, h0, cur);
    kgemm2<<<dim3(64 * (cur / 128)), dim3(256), 0, stream>>>(
        h0, W1T, smallB, pacc, cur);
    kfin<<<dim3((cur * 16 + 255) / 256), dim3(256), 0, stream>>>(
        pacc, smallB, out + (size_t)noff * 16, cur);
  }
}

// Round 10
// 267.993 us; speedup vs baseline: 1.1440x; 1.1031x over previous
//
#include <hip/hip_runtime.h>
#include <stdint.h>

typedef __bf16 bf16;
typedef __bf16 bf16x8 __attribute__((ext_vector_type(8)));
typedef float floatx4 __attribute__((ext_vector_type(4)));
typedef unsigned short u16;

#define PDIM 16

__device__ __forceinline__ floatx4 mfma_16x16x32(bf16x8 a, bf16x8 b, floatx4 c) {
  return __builtin_amdgcn_mfma_f32_16x16x32_bf16(a, b, c, 0, 0, 0);
}

// async 16B/lane global->LDS; LDS dst = wave-uniform base + lane*16.
__device__ __forceinline__ void stage16(const bf16* g, bf16* lds_base) {
  __builtin_amdgcn_global_load_lds(
      (const __attribute__((address_space(1))) void*)g,
      (__attribute__((address_space(3))) void*)lds_base, 16, 0, 0);
}

// ---- fused prep: [0,2048) transpose W0/W1; [2048,2048+nConvBlk) emb conv;
// then biases+W2 pack. All fp32 -> bf16. ----
__global__ __launch_bounds__(256) void kprep(const float* __restrict__ emb,
                                             const float* __restrict__ W0,
                                             const float* __restrict__ W1,
                                             const float* __restrict__ b0,
                                             const float* __restrict__ b1,
                                             const float* __restrict__ W2,
                                             const float* __restrict__ b2,
                                             bf16* __restrict__ embB,
                                             bf16* __restrict__ W0T,
                                             bf16* __restrict__ W1T,
                                             bf16* __restrict__ smallB,
                                             int n8, int nConvBlk) {
  __shared__ u16 tile[64][72];
  const int b = blockIdx.x;
  const int t = threadIdx.x;
  if (b < 2048) {
    const int m  = b >> 10;
    const int p  = (b >> 6) & 15;
    const int tr = (b >> 3) & 7;
    const int tc = b & 7;
    const float* src = (m ? W1 : W0) + ((size_t)p << 18);
    bf16*        dst = (m ? W1T : W0T) + ((size_t)p << 18);
#pragma unroll
    for (int i = 0; i < 2; ++i) {
      int c = t + i * 256;
      int r = c >> 3, s = c & 7;
      const float4* s32 =
          (const float4*)(src + (size_t)(tr * 64 + r) * 512 + tc * 64 + s * 8);
      float4 a = s32[0], bb = s32[1];
      bf16 o[8] = {(bf16)a.x, (bf16)a.y, (bf16)a.z, (bf16)a.w,
                   (bf16)bb.x, (bf16)bb.y, (bf16)bb.z, (bf16)bb.w};
      *(uint4*)&tile[r][s * 8] = *(uint4*)o;
    }
    __syncthreads();
#pragma unroll
    for (int i = 0; i < 2; ++i) {
      int c = t + i * 256;
      int r = c >> 3, s = c & 7;
      union { u16 u[8]; uint4 v; } tmp;
#pragma unroll
      for (int j = 0; j < 8; ++j) tmp.u[j] = tile[s * 8 + j][r];
      *(uint4*)(dst + (size_t)(tc * 64 + r) * 512 + tr * 64 + s * 8) = tmp.v;
    }
  } else if (b < 2048 + nConvBlk) {
    const int i = (b - 2048) * 256 + t;
    if (i < n8) {
      const float4* s = (const float4*)emb;
      float4 a = s[i * 2], bb = s[i * 2 + 1];
      bf16 o[8] = {(bf16)a.x, (bf16)a.y, (bf16)a.z, (bf16)a.w,
                   (bf16)bb.x, (bf16)bb.y, (bf16)bb.z, (bf16)bb.w};
      *(uint4*)(embB + (size_t)i * 8) = *(uint4*)o;
    }
  } else {
    const int j = (b - 2048 - nConvBlk) * 256 + t;
    if (j < 24592) {
      const float* src;
      int off;
      if (j < 8192)       { src = b0; off = j; }
      else if (j < 16384) { src = b1; off = j - 8192; }
      else if (j < 24576) { src = W2; off = j - 16384; }
      else                { src = b2; off = j - 24576; }
      smallB[j] = (bf16)src[off];
    }
  }
}

// ---- layer 0: h0 = relu(emb . W0T^T + b0), bf16 out.
// 128x128 tile, BK=32 (one MFMA K-step), single-barrier cross-iteration
// double-buffered async staging, 16x16x32 MFMA 4x4 acc (16 indep chains,
// conflict-floor fragment reads).
__global__ __launch_bounds__(256) void kgemm1(const bf16* __restrict__ emb,
                                              const bf16* __restrict__ W0T,
                                              const bf16* __restrict__ small,
                                              bf16* __restrict__ h0,
                                              int Nc) {
  __shared__ bf16 smem[16384];  // Ab[2][4096] | Bb[2][4096]; epilogue C 64x136
  const int b  = blockIdx.x;
  const int p  = b & 15;
  const int ht = (b >> 4) & 3;
  const int nt = b >> 6;
  const int n0 = nt * 128;
  const int hc0 = ht * 128;
  const int tid = threadIdx.x;
  const int w = tid >> 6;
  const int lane = tid & 63;
  const int q = lane >> 4;
  const int mm = lane & 15;
  const int wr = (w >> 1) * 64;
  const int wc = (w & 1) * 64;
  const int srow = lane >> 2;       // 0..15
  const int kch  = (lane & 3) * 8;  // 16B chunk within 32-elem row

  const bf16* Arow = emb + (size_t)n0 * 512;
  const bf16* Brow = W0T + ((size_t)p << 18) + (size_t)hc0 * 512;

  floatx4 acc[4][4];
#pragma unroll
  for (int i = 0; i < 4; ++i)
#pragma unroll
    for (int j = 0; j < 4; ++j) acc[i][j] = floatx4{0.f, 0.f, 0.f, 0.f};

  const int r0 = w * 16 + srow;
  // prologue: stage tile 0 into buffer 0
  stage16(Arow + (size_t)r0 * 512 + kch, smem + (w * 16) * 32);
  stage16(Arow + (size_t)(64 + r0) * 512 + kch, smem + (64 + w * 16) * 32);
  stage16(Brow + (size_t)r0 * 512 + kch, smem + 8192 + (w * 16) * 32);
  stage16(Brow + (size_t)(64 + r0) * 512 + kch, smem + 8192 + (64 + w * 16) * 32);

  for (int it = 0; it < 16; ++it) {
    __syncthreads();  // tile[it] landed; buf[it^1] fully consumed
    const int bb = it & 1;
    if (it + 1 < 16) {
      const int nb = (it + 1) & 1;
      const int kn = (it + 1) * 32;
      stage16(Arow + (size_t)r0 * 512 + kn + kch,
              smem + nb * 4096 + (w * 16) * 32);
      stage16(Arow + (size_t)(64 + r0) * 512 + kn + kch,
              smem + nb * 4096 + (64 + w * 16) * 32);
      stage16(Brow + (size_t)r0 * 512 + kn + kch,
              smem + 8192 + nb * 4096 + (w * 16) * 32);
      stage16(Brow + (size_t)(64 + r0) * 512 + kn + kch,
              smem + 8192 + nb * 4096 + (64 + w * 16) * 32);
    }
    const bf16* A = smem + bb * 4096;
    const bf16* B = smem + 8192 + bb * 4096;
    bf16x8 af[4], bv[4];
#pragma unroll
    for (int rt = 0; rt < 4; ++rt)
      af[rt] = *(const bf16x8*)&A[(wr + rt * 16 + mm) * 32 + q * 8];
#pragma unroll
    for (int ct = 0; ct < 4; ++ct)
      bv[ct] = *(const bf16x8*)&B[(wc + ct * 16 + mm) * 32 + q * 8];
#pragma unroll
    for (int rt = 0; rt < 4; ++rt)
#pragma unroll
      for (int ct = 0; ct < 4; ++ct)
        acc[rt][ct] = mfma_16x16x32(af[rt], bv[ct], acc[rt][ct]);
  }

  // coalesced epilogue via LDS (stride 136), two 64-row passes
  __syncthreads();
  bf16* Cst = smem;
#pragma unroll
  for (int pass = 0; pass < 2; ++pass) {
    if ((w >> 1) == pass) {
#pragma unroll
      for (int ct = 0; ct < 4; ++ct) {
        const float bvv = (float)small[p * 512 + hc0 + wc + ct * 16 + mm];
#pragma unroll
        for (int rt = 0; rt < 4; ++rt)
#pragma unroll
          for (int r = 0; r < 4; ++r) {
            float v = acc[rt][ct][r] + bvv;
            v = v > 0.f ? v : 0.f;
            Cst[(rt * 16 + q * 4 + r) * 136 + wc + ct * 16 + mm] = (bf16)v;
          }
      }
    }
    __syncthreads();
#pragma unroll
    for (int i = 0; i < 4; ++i) {
      const int row = (tid >> 4) + i * 16;
      const int chunk = tid & 15;
      uint4 v = *(const uint4*)&Cst[row * 136 + chunk * 8];
      *(uint4*)&h0[((size_t)p * Nc + n0 + pass * 64 + row) * 512 + hc0 +
                   chunk * 8] = v;
    }
    if (pass == 0) __syncthreads();
  }
}

// ---- layer 1 GEMM + fused partial layer-2 dot; same pipelined core ----
__global__ __launch_bounds__(256) void kgemm2(const bf16* __restrict__ h0,
                                              const bf16* __restrict__ W1T,
                                              const bf16* __restrict__ small,
                                              float* __restrict__ pacc,
                                              int Nc) {
  __shared__ bf16 smem[16384];
  __shared__ float oacc[128];
  const int b  = blockIdx.x;
  const int p  = b & 15;
  const int ht = (b >> 4) & 3;
  const int nt = b >> 6;
  const int n0 = nt * 128;
  const int hc0 = ht * 128;
  const int tid = threadIdx.x;
  const int w = tid >> 6;
  const int lane = tid & 63;
  const int q = lane >> 4;
  const int mm = lane & 15;
  const int wr = (w >> 1) * 64;
  const int wc = (w & 1) * 64;
  const int srow = lane >> 2;
  const int kch = (lane & 3) * 8;
  if (tid < 128) oacc[tid] = 0.f;

  const bf16* Arow = h0 + ((size_t)p * Nc + n0) * 512;
  const bf16* Brow = W1T + ((size_t)p << 18) + (size_t)hc0 * 512;

  floatx4 acc[4][4];
#pragma unroll
  for (int i = 0; i < 4; ++i)
#pragma unroll
    for (int j = 0; j < 4; ++j) acc[i][j] = floatx4{0.f, 0.f, 0.f, 0.f};

  const int r0 = w * 16 + srow;
  stage16(Arow + (size_t)r0 * 512 + kch, smem + (w * 16) * 32);
  stage16(Arow + (size_t)(64 + r0) * 512 + kch, smem + (64 + w * 16) * 32);
  stage16(Brow + (size_t)r0 * 512 + kch, smem + 8192 + (w * 16) * 32);
  stage16(Brow + (size_t)(64 + r0) * 512 + kch, smem + 8192 + (64 + w * 16) * 32);

  for (int it = 0; it < 16; ++it) {
    __syncthreads();
    const int bb = it & 1;
    if (it + 1 < 16) {
      const int nb = (it + 1) & 1;
      const int kn = (it + 1) * 32;
      stage16(Arow + (size_t)r0 * 512 + kn + kch,
              smem + nb * 4096 + (w * 16) * 32);
      stage16(Arow + (size_t)(64 + r0) * 512 + kn + kch,
              smem + nb * 4096 + (64 + w * 16) * 32);
      stage16(Brow + (size_t)r0 * 512 + kn + kch,
              smem + 8192 + nb * 4096 + (w * 16) * 32);
      stage16(Brow + (size_t)(64 + r0) * 512 + kn + kch,
              smem + 8192 + nb * 4096 + (64 + w * 16) * 32);
    }
    const bf16* A = smem + bb * 4096;
    const bf16* B = smem + 8192 + bb * 4096;
    bf16x8 af[4], bv[4];
#pragma unroll
    for (int rt = 0; rt < 4; ++rt)
      af[rt] = *(const bf16x8*)&A[(wr + rt * 16 + mm) * 32 + q * 8];
#pragma unroll
    for (int ct = 0; ct < 4; ++ct)
      bv[ct] = *(const bf16x8*)&B[(wc + ct * 16 + mm) * 32 + q * 8];
#pragma unroll
    for (int rt = 0; rt < 4; ++rt)
#pragma unroll
      for (int ct = 0; ct < 4; ++ct)
        acc[rt][ct] = mfma_16x16x32(af[rt], bv[ct], acc[rt][ct]);
  }

  // epilogue: h1 = relu(acc + b1); pd[row] += h1 * W2[col]
  float pd[4][4];
#pragma unroll
  for (int i = 0; i < 4; ++i)
#pragma unroll
    for (int r = 0; r < 4; ++r) pd[i][r] = 0.f;
#pragma unroll
  for (int ct = 0; ct < 4; ++ct) {
    const int col = hc0 + wc + ct * 16 + mm;
    const float b1v = (float)small[8192 + p * 512 + col];
    const float w2v = (float)small[16384 + p * 512 + col];
#pragma unroll
    for (int rt = 0; rt < 4; ++rt)
#pragma unroll
      for (int r = 0; r < 4; ++r) {
        float v = acc[rt][ct][r] + b1v;
        v = v > 0.f ? v : 0.f;
        pd[rt][r] += v * w2v;
      }
  }
  // reduce over the 16 col-lanes of each row tile, accumulate in LDS
#pragma unroll
  for (int rt = 0; rt < 4; ++rt)
#pragma unroll
    for (int r = 0; r < 4; ++r) {
      float v = pd[rt][r];
      v += __shfl_xor(v, 1, 16);
      v += __shfl_xor(v, 2, 16);
      v += __shfl_xor(v, 4, 16);
      v += __shfl_xor(v, 8, 16);
      if (mm == 0) atomicAdd(&oacc[wr + rt * 16 + q * 4 + r], v);
    }
  __syncthreads();
  if (tid < 128)
    pacc[(size_t)(p * 4 + ht) * Nc + n0 + tid] = oacc[tid];
}

// ---- finish: sum 4 ht partials + b2, sigmoid, fp32 out ----
__global__ __launch_bounds__(256) void kfin(const float* __restrict__ pacc,
                                            const bf16* __restrict__ small,
                                            float* __restrict__ out, int Nc) {
  const int idx = blockIdx.x * 256 + threadIdx.x;
  if (idx >= Nc * 16) return;
  const int n = idx >> 4;
  const int p = idx & 15;
  float v = (float)small[24576 + p];
#pragma unroll
  for (int ht = 0; ht < 4; ++ht) v += pacc[(size_t)(p * 4 + ht) * Nc + n];
  out[(size_t)n * 16 + p] = 1.f / (1.f + expf(-v));
}

// ---- fallback (tiny ws / odd N): slow but correct, fp32 in/out ----
__global__ __launch_bounds__(64) void knaive(const float* __restrict__ emb,
                                             const float* __restrict__ W0,
                                             const float* __restrict__ b0,
                                             const float* __restrict__ W1,
                                             const float* __restrict__ b1,
                                             const float* __restrict__ W2,
                                             const float* __restrict__ b2,
                                             float* __restrict__ out) {
  const int n = blockIdx.x >> 4;
  const int p = blockIdx.x & 15;
  __shared__ float h0s[512];
  __shared__ float h1s[512];
  const size_t wb = (size_t)p << 18;
  const int t = threadIdx.x;
  for (int h = t; h < 512; h += 64) {
    float a = 0.f;
    for (int e = 0; e < 512; ++e)
      a += emb[(size_t)n * 512 + e] * W0[wb + (size_t)e * 512 + h];
    a += b0[p * 512 + h];
    h0s[h] = a > 0.f ? a : 0.f;
  }
  __syncthreads();
  for (int k = t; k < 512; k += 64) {
    float a = 0.f;
    for (int hh = 0; hh < 512; ++hh)
      a += h0s[hh] * W1[wb + (size_t)hh * 512 + k];
    a += b1[p * 512 + k];
    h1s[k] = a > 0.f ? a : 0.f;
  }
  __syncthreads();
  float s = 0.f;
  for (int k = t; k < 512; k += 64) s += h1s[k] * W2[p * 512 + k];
  for (int off = 32; off; off >>= 1) s += __shfl_down(s, off, 64);
  if (t == 0)
    out[(size_t)n * 16 + p] = 1.f / (1.f + expf(-(s + b2[p])));
}

extern "C" void kernel_launch(void* const* d_in, const int* in_sizes, int n_in,
                              void* d_out, int out_size, void* d_ws, size_t ws_size,
                              hipStream_t stream) {
  (void)n_in; (void)out_size;
  const float* emb = (const float*)d_in[0];
  const float* W0  = (const float*)d_in[1];
  const float* b0  = (const float*)d_in[2];
  const float* W1  = (const float*)d_in[3];
  const float* b1  = (const float*)d_in[4];
  const float* W2  = (const float*)d_in[5];
  const float* b2  = (const float*)d_in[6];
  float* out = (float*)d_out;

  const int N = in_sizes[0] / 512;

  char* ws = (char*)d_ws;
  bf16*  W0T    = (bf16*)ws;                                 // 8 MB
  bf16*  W1T    = (bf16*)(ws + (8ll << 20));                 // 8 MB
  bf16*  smallB = (bf16*)(ws + (16ll << 20));                // 64 KB
  float* pacc   = (float*)(ws + (16ll << 20) + 65536);       // 256*N B
  bf16*  embB   = (bf16*)(ws + (16ll << 20) + 65536 + (size_t)N * 256);
  bf16*  h0     = (bf16*)(ws + (16ll << 20) + 65536 + (size_t)N * 256 +
                          (size_t)N * 1024);
  const long long fixed = (16ll << 20) + 65536 + (long long)N * 256 +
                          (long long)N * 1024;
  long long avail = (long long)ws_size - fixed;
  long long rows = avail > 0 ? avail / (16 * 512 * 2) : 0;
  int Nc = (int)((rows / 128) * 128);
  if (Nc > N) Nc = N;

  if (Nc < 128 || (N % 128) != 0) {
    knaive<<<dim3(N * PDIM), dim3(64), 0, stream>>>(emb, W0, b0, W1, b1, W2,
                                                    b2, out);
    return;
  }

  const int n8 = N * 512 / 8;
  const int nConvBlk = (n8 + 255) / 256;
  kprep<<<dim3(2048 + nConvBlk + 97), dim3(256), 0, stream>>>(
      emb, W0, W1, b0, b1, W2, b2, embB, W0T, W1T, smallB, n8, nConvBlk);

  for (int noff = 0; noff < N; noff += Nc) {
    const int cur = (N - noff < Nc) ? (N - noff) : Nc;
    kgemm1<<<dim3(64 * (cur / 128)), dim3(256), 0, stream>>>(
        embB + (size_t)noff * 512, W0T, smallB, h0, cur);
    kgemm2<<<dim3(64 * (cur / 128)), dim3(256), 0, stream>>>(
        h0, W1T, smallB, pacc, cur);
    kfin<<<dim3((cur * 16 + 255) / 256), dim3(256), 0, stream>>>(
        pacc, smallB, out + (size_t)noff * 16, cur);
  }
}

// Round 11
// 267.258 us; speedup vs baseline: 1.1471x; 1.0027x over previous
//
#include <hip/hip_runtime.h>
#include <stdint.h>

typedef __bf16 bf16;
typedef __bf16 bf16x8 __attribute__((ext_vector_type(8)));
typedef float floatx4 __attribute__((ext_vector_type(4)));
typedef unsigned short u16;

#define PDIM 16

__device__ __forceinline__ floatx4 mfma_16x16x32(bf16x8 a, bf16x8 b, floatx4 c) {
  return __builtin_amdgcn_mfma_f32_16x16x32_bf16(a, b, c, 0, 0, 0);
}

// async 16B/lane global->LDS; LDS dst = wave-uniform base + lane*16.
__device__ __forceinline__ void stage16(const bf16* g, bf16* lds_base) {
  __builtin_amdgcn_global_load_lds(
      (const __attribute__((address_space(1))) void*)g,
      (__attribute__((address_space(3))) void*)lds_base, 16, 0, 0);
}

// raw barrier + fine-grained vmcnt (hipBLASLt-style pipeline control).
#define WAITVM4() asm volatile("s_waitcnt vmcnt(4)" ::: "memory")
#define WAITVM0() asm volatile("s_waitcnt vmcnt(0)" ::: "memory")
#define BAR()     asm volatile("s_barrier" ::: "memory")

// ---- fused prep: [0,2048) transpose W0/W1; [2048,2048+nConvBlk) emb conv;
// then biases+W2 pack. All fp32 -> bf16. ----
__global__ __launch_bounds__(256) void kprep(const float* __restrict__ emb,
                                             const float* __restrict__ W0,
                                             const float* __restrict__ W1,
                                             const float* __restrict__ b0,
                                             const float* __restrict__ b1,
                                             const float* __restrict__ W2,
                                             const float* __restrict__ b2,
                                             bf16* __restrict__ embB,
                                             bf16* __restrict__ W0T,
                                             bf16* __restrict__ W1T,
                                             bf16* __restrict__ smallB,
                                             int n8, int nConvBlk) {
  __shared__ u16 tile[64][72];
  const int b = blockIdx.x;
  const int t = threadIdx.x;
  if (b < 2048) {
    const int m  = b >> 10;
    const int p  = (b >> 6) & 15;
    const int tr = (b >> 3) & 7;
    const int tc = b & 7;
    const float* src = (m ? W1 : W0) + ((size_t)p << 18);
    bf16*        dst = (m ? W1T : W0T) + ((size_t)p << 18);
#pragma unroll
    for (int i = 0; i < 2; ++i) {
      int c = t + i * 256;
      int r = c >> 3, s = c & 7;
      const float4* s32 =
          (const float4*)(src + (size_t)(tr * 64 + r) * 512 + tc * 64 + s * 8);
      float4 a = s32[0], bb = s32[1];
      bf16 o[8] = {(bf16)a.x, (bf16)a.y, (bf16)a.z, (bf16)a.w,
                   (bf16)bb.x, (bf16)bb.y, (bf16)bb.z, (bf16)bb.w};
      *(uint4*)&tile[r][s * 8] = *(uint4*)o;
    }
    __syncthreads();
#pragma unroll
    for (int i = 0; i < 2; ++i) {
      int c = t + i * 256;
      int r = c >> 3, s = c & 7;
      union { u16 u[8]; uint4 v; } tmp;
#pragma unroll
      for (int j = 0; j < 8; ++j) tmp.u[j] = tile[s * 8 + j][r];
      *(uint4*)(dst + (size_t)(tc * 64 + r) * 512 + tr * 64 + s * 8) = tmp.v;
    }
  } else if (b < 2048 + nConvBlk) {
    const int i = (b - 2048) * 256 + t;
    if (i < n8) {
      const float4* s = (const float4*)emb;
      float4 a = s[i * 2], bb = s[i * 2 + 1];
      bf16 o[8] = {(bf16)a.x, (bf16)a.y, (bf16)a.z, (bf16)a.w,
                   (bf16)bb.x, (bf16)bb.y, (bf16)bb.z, (bf16)bb.w};
      *(uint4*)(embB + (size_t)i * 8) = *(uint4*)o;
    }
  } else {
    const int j = (b - 2048 - nConvBlk) * 256 + t;
    if (j < 24592) {
      const float* src;
      int off;
      if (j < 8192)       { src = b0; off = j; }
      else if (j < 16384) { src = b1; off = j - 8192; }
      else if (j < 24576) { src = W2; off = j - 16384; }
      else                { src = b2; off = j - 24576; }
      smallB[j] = (bf16)src[off];
    }
  }
}

// ---- layer 0: h0 = relu(emb . W0T^T + b0), bf16 out.
// 128x128 tile, BK=32, 16x16x32 MFMA 4x4 acc; TRIPLE-buffered distance-2
// async staging with raw s_barrier + s_waitcnt vmcnt(4) (never full drain):
// per iter: wait own tile-it DMAs (issued 2 phases ago) -> barrier (all waves'
// tile-it landed + buf[(it-1)%3] free) -> issue tile it+2 -> compute.
__global__ __launch_bounds__(256) void kgemm1(const bf16* __restrict__ emb,
                                              const bf16* __restrict__ W0T,
                                              const bf16* __restrict__ small,
                                              bf16* __restrict__ h0,
                                              int Nc) {
  __shared__ bf16 smem[24576];  // A: 3x4096 @0 | B: 3x4096 @12288; epi C 64x136
  const int b  = blockIdx.x;
  const int p  = b & 15;
  const int ht = (b >> 4) & 3;
  const int nt = b >> 6;
  const int n0 = nt * 128;
  const int hc0 = ht * 128;
  const int tid = threadIdx.x;
  const int w = tid >> 6;
  const int lane = tid & 63;
  const int q = lane >> 4;
  const int mm = lane & 15;
  const int wr = (w >> 1) * 64;
  const int wc = (w & 1) * 64;
  const int srow = lane >> 2;
  const int kch  = (lane & 3) * 8;

  const bf16* Arow = emb + (size_t)n0 * 512;
  const bf16* Brow = W0T + ((size_t)p << 18) + (size_t)hc0 * 512;

  floatx4 acc[4][4];
#pragma unroll
  for (int i = 0; i < 4; ++i)
#pragma unroll
    for (int j = 0; j < 4; ++j) acc[i][j] = floatx4{0.f, 0.f, 0.f, 0.f};

  const int r0 = w * 16 + srow;
  // prologue: tile 0 -> buf0, tile 1 -> buf1 (4 DMAs per group, in order)
#pragma unroll
  for (int tpre = 0; tpre < 2; ++tpre) {
    const int kn = tpre * 32;
    bf16* Ab = smem + tpre * 4096;
    bf16* Bb = smem + 12288 + tpre * 4096;
    stage16(Arow + (size_t)r0 * 512 + kn + kch, Ab + (w * 16) * 32);
    stage16(Arow + (size_t)(64 + r0) * 512 + kn + kch, Ab + (64 + w * 16) * 32);
    stage16(Brow + (size_t)r0 * 512 + kn + kch, Bb + (w * 16) * 32);
    stage16(Brow + (size_t)(64 + r0) * 512 + kn + kch, Bb + (64 + w * 16) * 32);
  }

#pragma unroll
  for (int it = 0; it < 16; ++it) {
    if (it < 15) { WAITVM4(); } else { WAITVM0(); }  // own tile-it landed
    BAR();  // all waves: tile-it landed; buf[(it+2)%3] no longer being read
    if (it + 2 < 16) {
      const int nb = (it + 2) % 3;
      const int kn = (it + 2) * 32;
      bf16* Ab = smem + nb * 4096;
      bf16* Bb = smem + 12288 + nb * 4096;
      stage16(Arow + (size_t)r0 * 512 + kn + kch, Ab + (w * 16) * 32);
      stage16(Arow + (size_t)(64 + r0) * 512 + kn + kch, Ab + (64 + w * 16) * 32);
      stage16(Brow + (size_t)r0 * 512 + kn + kch, Bb + (w * 16) * 32);
      stage16(Brow + (size_t)(64 + r0) * 512 + kn + kch, Bb + (64 + w * 16) * 32);
    }
    const int cb = it % 3;
    const bf16* A = smem + cb * 4096;
    const bf16* B = smem + 12288 + cb * 4096;
    bf16x8 af[4], bv[4];
#pragma unroll
    for (int rt = 0; rt < 4; ++rt)
      af[rt] = *(const bf16x8*)&A[(wr + rt * 16 + mm) * 32 + q * 8];
#pragma unroll
    for (int ct = 0; ct < 4; ++ct)
      bv[ct] = *(const bf16x8*)&B[(wc + ct * 16 + mm) * 32 + q * 8];
#pragma unroll
    for (int rt = 0; rt < 4; ++rt)
#pragma unroll
      for (int ct = 0; ct < 4; ++ct)
        acc[rt][ct] = mfma_16x16x32(af[rt], bv[ct], acc[rt][ct]);
  }

  // coalesced epilogue via LDS (stride 136), two 64-row passes
  __syncthreads();
  bf16* Cst = smem;
#pragma unroll
  for (int pass = 0; pass < 2; ++pass) {
    if ((w >> 1) == pass) {
#pragma unroll
      for (int ct = 0; ct < 4; ++ct) {
        const float bvv = (float)small[p * 512 + hc0 + wc + ct * 16 + mm];
#pragma unroll
        for (int rt = 0; rt < 4; ++rt)
#pragma unroll
          for (int r = 0; r < 4; ++r) {
            float v = acc[rt][ct][r] + bvv;
            v = v > 0.f ? v : 0.f;
            Cst[(rt * 16 + q * 4 + r) * 136 + wc + ct * 16 + mm] = (bf16)v;
          }
      }
    }
    __syncthreads();
#pragma unroll
    for (int i = 0; i < 4; ++i) {
      const int row = (tid >> 4) + i * 16;
      const int chunk = tid & 15;
      uint4 v = *(const uint4*)&Cst[row * 136 + chunk * 8];
      *(uint4*)&h0[((size_t)p * Nc + n0 + pass * 64 + row) * 512 + hc0 +
                   chunk * 8] = v;
    }
    if (pass == 0) __syncthreads();
  }
}

// ---- layer 1 GEMM + fused partial layer-2 dot; same pipelined core ----
__global__ __launch_bounds__(256) void kgemm2(const bf16* __restrict__ h0,
                                              const bf16* __restrict__ W1T,
                                              const bf16* __restrict__ small,
                                              float* __restrict__ pacc,
                                              int Nc) {
  __shared__ bf16 smem[24576];
  __shared__ float oacc[128];
  const int b  = blockIdx.x;
  const int p  = b & 15;
  const int ht = (b >> 4) & 3;
  const int nt = b >> 6;
  const int n0 = nt * 128;
  const int hc0 = ht * 128;
  const int tid = threadIdx.x;
  const int w = tid >> 6;
  const int lane = tid & 63;
  const int q = lane >> 4;
  const int mm = lane & 15;
  const int wr = (w >> 1) * 64;
  const int wc = (w & 1) * 64;
  const int srow = lane >> 2;
  const int kch = (lane & 3) * 8;
  if (tid < 128) oacc[tid] = 0.f;

  const bf16* Arow = h0 + ((size_t)p * Nc + n0) * 512;
  const bf16* Brow = W1T + ((size_t)p << 18) + (size_t)hc0 * 512;

  floatx4 acc[4][4];
#pragma unroll
  for (int i = 0; i < 4; ++i)
#pragma unroll
    for (int j = 0; j < 4; ++j) acc[i][j] = floatx4{0.f, 0.f, 0.f, 0.f};

  const int r0 = w * 16 + srow;
#pragma unroll
  for (int tpre = 0; tpre < 2; ++tpre) {
    const int kn = tpre * 32;
    bf16* Ab = smem + tpre * 4096;
    bf16* Bb = smem + 12288 + tpre * 4096;
    stage16(Arow + (size_t)r0 * 512 + kn + kch, Ab + (w * 16) * 32);
    stage16(Arow + (size_t)(64 + r0) * 512 + kn + kch, Ab + (64 + w * 16) * 32);
    stage16(Brow + (size_t)r0 * 512 + kn + kch, Bb + (w * 16) * 32);
    stage16(Brow + (size_t)(64 + r0) * 512 + kn + kch, Bb + (64 + w * 16) * 32);
  }

#pragma unroll
  for (int it = 0; it < 16; ++it) {
    if (it < 15) { WAITVM4(); } else { WAITVM0(); }
    BAR();
    if (it + 2 < 16) {
      const int nb = (it + 2) % 3;
      const int kn = (it + 2) * 32;
      bf16* Ab = smem + nb * 4096;
      bf16* Bb = smem + 12288 + nb * 4096;
      stage16(Arow + (size_t)r0 * 512 + kn + kch, Ab + (w * 16) * 32);
      stage16(Arow + (size_t)(64 + r0) * 512 + kn + kch, Ab + (64 + w * 16) * 32);
      stage16(Brow + (size_t)r0 * 512 + kn + kch, Bb + (w * 16) * 32);
      stage16(Brow + (size_t)(64 + r0) * 512 + kn + kch, Bb + (64 + w * 16) * 32);
    }
    const int cb = it % 3;
    const bf16* A = smem + cb * 4096;
    const bf16* B = smem + 12288 + cb * 4096;
    bf16x8 af[4], bv[4];
#pragma unroll
    for (int rt = 0; rt < 4; ++rt)
      af[rt] = *(const bf16x8*)&A[(wr + rt * 16 + mm) * 32 + q * 8];
#pragma unroll
    for (int ct = 0; ct < 4; ++ct)
      bv[ct] = *(const bf16x8*)&B[(wc + ct * 16 + mm) * 32 + q * 8];
#pragma unroll
    for (int rt = 0; rt < 4; ++rt)
#pragma unroll
      for (int ct = 0; ct < 4; ++ct)
        acc[rt][ct] = mfma_16x16x32(af[rt], bv[ct], acc[rt][ct]);
  }

  // epilogue: h1 = relu(acc + b1); pd[row] += h1 * W2[col]
  float pd[4][4];
#pragma unroll
  for (int i = 0; i < 4; ++i)
#pragma unroll
    for (int r = 0; r < 4; ++r) pd[i][r] = 0.f;
#pragma unroll
  for (int ct = 0; ct < 4; ++ct) {
    const int col = hc0 + wc + ct * 16 + mm;
    const float b1v = (float)small[8192 + p * 512 + col];
    const float w2v = (float)small[16384 + p * 512 + col];
#pragma unroll
    for (int rt = 0; rt < 4; ++rt)
#pragma unroll
      for (int r = 0; r < 4; ++r) {
        float v = acc[rt][ct][r] + b1v;
        v = v > 0.f ? v : 0.f;
        pd[rt][r] += v * w2v;
      }
  }
#pragma unroll
  for (int rt = 0; rt < 4; ++rt)
#pragma unroll
    for (int r = 0; r < 4; ++r) {
      float v = pd[rt][r];
      v += __shfl_xor(v, 1, 16);
      v += __shfl_xor(v, 2, 16);
      v += __shfl_xor(v, 4, 16);
      v += __shfl_xor(v, 8, 16);
      if (mm == 0) atomicAdd(&oacc[wr + rt * 16 + q * 4 + r], v);
    }
  __syncthreads();
  if (tid < 128)
    pacc[(size_t)(p * 4 + ht) * Nc + n0 + tid] = oacc[tid];
}

// ---- finish: sum 4 ht partials + b2, sigmoid, fp32 out ----
__global__ __launch_bounds__(256) void kfin(const float* __restrict__ pacc,
                                            const bf16* __restrict__ small,
                                            float* __restrict__ out, int Nc) {
  const int idx = blockIdx.x * 256 + threadIdx.x;
  if (idx >= Nc * 16) return;
  const int n = idx >> 4;
  const int p = idx & 15;
  float v = (float)small[24576 + p];
#pragma unroll
  for (int ht = 0; ht < 4; ++ht) v += pacc[(size_t)(p * 4 + ht) * Nc + n];
  out[(size_t)n * 16 + p] = 1.f / (1.f + expf(-v));
}

// ---- fallback (tiny ws / odd N): slow but correct, fp32 in/out ----
__global__ __launch_bounds__(64) void knaive(const float* __restrict__ emb,
                                             const float* __restrict__ W0,
                                             const float* __restrict__ b0,
                                             const float* __restrict__ W1,
                                             const float* __restrict__ b1,
                                             const float* __restrict__ W2,
                                             const float* __restrict__ b2,
                                             float* __restrict__ out) {
  const int n = blockIdx.x >> 4;
  const int p = blockIdx.x & 15;
  __shared__ float h0s[512];
  __shared__ float h1s[512];
  const size_t wb = (size_t)p << 18;
  const int t = threadIdx.x;
  for (int h = t; h < 512; h += 64) {
    float a = 0.f;
    for (int e = 0; e < 512; ++e)
      a += emb[(size_t)n * 512 + e] * W0[wb + (size_t)e * 512 + h];
    a += b0[p * 512 + h];
    h0s[h] = a > 0.f ? a : 0.f;
  }
  __syncthreads();
  for (int k = t; k < 512; k += 64) {
    float a = 0.f;
    for (int hh = 0; hh < 512; ++hh)
      a += h0s[hh] * W1[wb + (size_t)hh * 512 + k];
    a += b1[p * 512 + k];
    h1s[k] = a > 0.f ? a : 0.f;
  }
  __syncthreads();
  float s = 0.f;
  for (int k = t; k < 512; k += 64) s += h1s[k] * W2[p * 512 + k];
  for (int off = 32; off; off >>= 1) s += __shfl_down(s, off, 64);
  if (t == 0)
    out[(size_t)n * 16 + p] = 1.f / (1.f + expf(-(s + b2[p])));
}

extern "C" void kernel_launch(void* const* d_in, const int* in_sizes, int n_in,
                              void* d_out, int out_size, void* d_ws, size_t ws_size,
                              hipStream_t stream) {
  (void)n_in; (void)out_size;
  const float* emb = (const float*)d_in[0];
  const float* W0  = (const float*)d_in[1];
  const float* b0  = (const float*)d_in[2];
  const float* W1  = (const float*)d_in[3];
  const float* b1  = (const float*)d_in[4];
  const float* W2  = (const float*)d_in[5];
  const float* b2  = (const float*)d_in[6];
  float* out = (float*)d_out;

  const int N = in_sizes[0] / 512;

  char* ws = (char*)d_ws;
  bf16*  W0T    = (bf16*)ws;                                 // 8 MB
  bf16*  W1T    = (bf16*)(ws + (8ll << 20));                 // 8 MB
  bf16*  smallB = (bf16*)(ws + (16ll << 20));                // 64 KB
  float* pacc   = (float*)(ws + (16ll << 20) + 65536);       // 256*N B
  bf16*  embB   = (bf16*)(ws + (16ll << 20) + 65536 + (size_t)N * 256);
  bf16*  h0     = (bf16*)(ws + (16ll << 20) + 65536 + (size_t)N * 256 +
                          (size_t)N * 1024);
  const long long fixed = (16ll << 20) + 65536 + (long long)N * 256 +
                          (long long)N * 1024;
  long long avail = (long long)ws_size - fixed;
  long long rows = avail > 0 ? avail / (16 * 512 * 2) : 0;
  int Nc = (int)((rows / 128) * 128);
  if (Nc > N) Nc = N;

  if (Nc < 128 || (N % 128) != 0) {
    knaive<<<dim3(N * PDIM), dim3(64), 0, stream>>>(emb, W0, b0, W1, b1, W2,
                                                    b2, out);
    return;
  }

  const int n8 = N * 512 / 8;
  const int nConvBlk = (n8 + 255) / 256;
  kprep<<<dim3(2048 + nConvBlk + 97), dim3(256), 0, stream>>>(
      emb, W0, W1, b0, b1, W2, b2, embB, W0T, W1T, smallB, n8, nConvBlk);

  for (int noff = 0; noff < N; noff += Nc) {
    const int cur = (N - noff < Nc) ? (N - noff) : Nc;
    kgemm1<<<dim3(64 * (cur / 128)), dim3(256), 0, stream>>>(
        embB + (size_t)noff * 512, W0T, smallB, h0, cur);
    kgemm2<<<dim3(64 * (cur / 128)), dim3(256), 0, stream>>>(
        h0, W1T, smallB, pacc, cur);
    kfin<<<dim3((cur * 16 + 255) / 256), dim3(256), 0, stream>>>(
        pacc, smallB, out + (size_t)noff * 16, cur);
  }
}